// Round 5
// baseline (681.293 us; speedup 1.0000x reference)
//
#include <hip/hip_runtime.h>
#include <math.h>

#define NWAY 5
#define NSUP 25
#define NZV  125
#define DF   640
#define NQ   75
#define TPB  320

// ---------------- shared-memory offsets for qp_kernel (in doubles) ----------
#define OFF_HINV 0      // 5 * 25*26 = 3250
#define OFF_WINV 3250   // 650
#define OFF_X    3900
#define OFF_S    4028
#define OFF_Z    4156
#define OFF_BX   4284
#define OFF_RX   4412
#define OFF_RZ   4540
#define OFF_TT   4668
#define OFF_C1   4796
#define OFF_DD   4924
#define OFF_VV   5052
#define OFF_DXA  5180
#define OFF_DSA  5308
#define OFF_DZA  5436
#define OFF_RSC  5564
#define OFF_DXC  5692
#define OFF_DSC  5820
#define OFF_DZC  5948
#define OFF_YV   6076   // 32 each from here
#define OFF_RY   6108
#define OFF_C2   6140
#define OFF_GG   6172
#define OFF_DYA  6204
#define OFF_DYC  6236
#define OFF_Z125 6268   // 128 zeros
#define OFF_Z25  6396   // 32 zeros
#define OFF_SC   6428   // scalars: [0]=best_res [1]=better flag [15]=reduce slot
#define SH_TOT   6448

__device__ __forceinline__ float simple_tf(float x) {
  float tp = fmaxf(x, 0.0f) + 1e-5f;
  float tn = fmaxf(-x, 0.0f) + 1e-5f;
  float lp = __logf(1.0f / tp + 1.0f);
  float ln_ = __logf(1.0f / tn + 1.0f);
  float pos = __expf(-1.3f * __logf(lp));
  float neg = __expf(-1.3f * __logf(ln_));
  return pos - neg;
}

// =====================================================================
// Kernel 1: transform + l2norm train features, Gram K, M = K + I (fp64)
// =====================================================================
__global__ void __launch_bounds__(TPB, 2) feat_kernel(
    const float* __restrict__ train, const int* __restrict__ usimple,
    double* __restrict__ Mg) {
  const int b = blockIdx.x;
  const int tid = threadIdx.x;
  const int lane = tid & 63;
  const int w = tid >> 6;
  __shared__ __align__(16) float ftn[NSUP * 644];   // padded stride 644
  const bool us = (usimple[0] != 0);
  const float* tb = train + (size_t)b * NSUP * DF;

  for (int idx = tid; idx < NSUP * DF; idx += TPB) {
    float v = tb[idx];
    if (us) v = simple_tf(v);
    int r = idx / DF, c = idx - r * DF;
    ftn[r * 644 + c] = v;
  }
  __syncthreads();
#pragma unroll
  for (int jj = 0; jj < 5; ++jj) {
    const int r = w + 5 * jj;
    float acc = 0.0f;
#pragma unroll
    for (int c = 0; c < 10; ++c) {
      float t = ftn[r * 644 + lane + 64 * c];
      acc += t * t;
    }
#pragma unroll
    for (int off = 32; off > 0; off >>= 1) acc += __shfl_xor(acc, off);
    const float sc = 1.0f / fmaxf(sqrtf(acc), 1e-12f);
#pragma unroll
    for (int c = 0; c < 10; ++c) ftn[r * 644 + lane + 64 * c] *= sc;
  }
  __syncthreads();
  double* Mb = Mg + (size_t)b * 650;
  for (int pi = tid; pi < 325; pi += TPB) {
    int i = 0, rem = pi;
    while (rem >= NSUP - i) { rem -= NSUP - i; ++i; }
    const int j = i + rem;
    const float4* ra = (const float4*)(ftn + i * 644);
    const float4* rb = (const float4*)(ftn + j * 644);
    double acc = 0.0;
    for (int c = 0; c < 160; ++c) {
      float4 av = ra[c], bv = rb[c];
      acc += (double)av.x * bv.x + (double)av.y * bv.y +
             (double)av.z * bv.z + (double)av.w * bv.w;
    }
    if (i == j) acc += 1.0;
    Mb[i * 26 + j] = acc;
    if (i != j) Mb[j * 26 + i] = acc;
  }
}

// =====================================================================
// Constant-lane fp64 broadcast via v_readlane (VALU, off the LDS pipe).
// The R4 GJ used __shfl (2x ds_bpermute per double): ~7.5k LDS-pipe ops
// per wave saturated the DS pipe (the 258us). readlane with a
// compile-time lane index is a cheap VALU->SGPR broadcast.
// =====================================================================
__device__ __forceinline__ double bcastd(double v, const int srclane) {
  const int lo = __builtin_amdgcn_readlane(__double2loint(v), srclane);
  const int hi = __builtin_amdgcn_readlane(__double2hiint(v), srclane);
  return __hiloint2double(hi, lo);
}

// In-place Gauss-Jordan inversion of a 25x25 SPD matrix.
// Layout: lane = COLUMN c (lanes 0..24); a[r] = A[r][c]. One 25-double
// register array (no spill; R4-verified). No pivoting: SPD fp64.
template <int J>
__device__ __forceinline__ void gj_pivot(double (&a)[25], const int lane) {
  const double djj = bcastd(a[J], J);
  const double pinv = 1.0 / djj;
  a[J] = ((lane == J) ? 1.0 : a[J]) * pinv;   // scale row J (lane J -> pinv)
#pragma unroll
  for (int r = 0; r < 25; ++r) {
    if (r != J) {
      const double f = bcastd(a[r], J);       // A[r][J] before update
      a[r] = ((lane == J) ? 0.0 : a[r]) - f * a[J];
    }
  }
}
template <int J>
__device__ __forceinline__ void gj_all(double (&a)[25], const int lane) {
  if constexpr (J < 25) {
    gj_pivot<J>(a, lane);
    gj_all<J + 1>(a, lane);
  }
}
__device__ __forceinline__ void gjinv25(double (&a)[25], const int lane) {
  gj_all<0>(a, lane);   // a[] now holds column `lane` of A^{-1}
}

__device__ __forceinline__ void factorize(const double* Msh, double* SH,
                                          const int tid) {
  const int lane = tid & 63;
  const int w = tid >> 6;
  const double* dd = SH + OFF_DD;
  double* Hinv = SH + OFF_HINV;
  double* Winv = SH + OFF_WINV;
  {
    double a[25];
#pragma unroll
    for (int j = 0; j < 25; ++j) a[j] = 0.0;
    if (lane < 25) {
      // lane = column; M symmetric so row-read works for column load
#pragma unroll
      for (int j = 0; j < 25; ++j)
        a[j] = Msh[lane * 26 + j] + ((j == lane) ? dd[lane * 5 + w] : 0.0);
    }
    gjinv25(a, lane);
    if (lane < 25) {
#pragma unroll
      for (int i = 0; i < 25; ++i) Hinv[w * 650 + i * 26 + lane] = a[i];
    }
  }
  __syncthreads();
  for (int idx = tid; idx < 625; idx += TPB) {
    const int i = idx / 25, r = idx - i * 25;
    double acc = 0.0;
#pragma unroll
    for (int k = 0; k < 5; ++k) acc += Hinv[k * 650 + i * 26 + r];
    Winv[i * 26 + r] = acc;
  }
  __syncthreads();
  if (w == 0) {
    double a[25];
#pragma unroll
    for (int j = 0; j < 25; ++j) a[j] = 0.0;
    if (lane < 25) {
#pragma unroll
      for (int j = 0; j < 25; ++j) a[j] = Winv[lane * 26 + j];
    }
    gjinv25(a, lane);
    if (lane < 25) {
#pragma unroll
      for (int i = 0; i < 25; ++i) Winv[i * 26 + lane] = a[i];
    }
  }
  __syncthreads();
}

__device__ __forceinline__ void kkt_solve(
    const double* Msh, double* SH, const double* rx, const double* rs,
    const double* rz, const double* ry, double* dx, double* ds, double* dz,
    double* dy, const int tid) {
  const int lane = tid & 63;
  const int w = tid >> 6;
  const double* dd = SH + OFF_DD;
  const double* Hinv = SH + OFF_HINV;
  const double* Winv = SH + OFF_WINV;
  double* tt = SH + OFF_TT;
  double* c1 = SH + OFF_C1;
  double* c2 = SH + OFF_C2;
  double* vv = SH + OFF_VV;
  double* gg = SH + OFF_GG;

  if (tid < NZV) tt[tid] = rz[tid] - rs[tid] / dd[tid];
  __syncthreads();
  if (tid < NZV) {
    const int i = tid / 5, k = tid - i * 5;
    double acc = -rx[tid];
#pragma unroll
    for (int j = 0; j < 25; ++j) acc += Msh[i * 26 + j] * tt[j * 5 + k];
    c1[tid] = acc;
  } else if (tid >= 128 && tid < 153) {
    const int i = tid - 128;
    double acc = -ry[i];
#pragma unroll
    for (int k = 0; k < 5; ++k) acc += tt[i * 5 + k];
    c2[i] = acc;
  }
  __syncthreads();
  if (lane < 25) {
    double acc = 0.0;
#pragma unroll
    for (int j = 0; j < 25; ++j)
      acc += Hinv[w * 650 + lane * 26 + j] * c1[j * 5 + w];
    vv[lane * 5 + w] = acc;
  }
  __syncthreads();
  if (tid < 25) {
    double acc = -c2[tid];
#pragma unroll
    for (int k = 0; k < 5; ++k) acc += vv[tid * 5 + k];
    gg[tid] = acc;
  }
  __syncthreads();
  if (tid < 25) {
    double acc = 0.0;
#pragma unroll
    for (int r = 0; r < 25; ++r) acc += Winv[tid * 26 + r] * gg[r];
    dy[tid] = acc;
  }
  __syncthreads();
  if (lane < 25) {
    double acc = 0.0;
#pragma unroll
    for (int j = 0; j < 25; ++j) acc += Hinv[w * 650 + lane * 26 + j] * dy[j];
    const int v = lane * 5 + w;
    const double u = vv[v] - acc;
    const double dzv = dd[v] * u;
    dz[v] = dzv;
    dx[v] = u - tt[v];
    ds[v] = (-rs[v] - dzv) / dd[v];
  }
  __syncthreads();
}

__device__ __forceinline__ double bred(const double* buf, int n, int ismin,
                                       double* SC, const int tid) {
  __syncthreads();
  if (tid < 64) {
    double acc = ismin ? 1e300 : 0.0;
    for (int m = tid; m < n; m += 64) {
      const double v = buf[m];
      acc = ismin ? fmin(acc, v) : (acc + v);
    }
#pragma unroll
    for (int off = 32; off > 0; off >>= 1) {
      const double o = __shfl_xor(acc, off);
      acc = ismin ? fmin(acc, o) : (acc + o);
    }
    if (tid == 0) SC[15] = acc;
  }
  __syncthreads();
  return SC[15];
}

__global__ void __launch_bounds__(TPB, 2) qp_kernel(
    const double* __restrict__ Mg, float* __restrict__ xout) {
  const int b = blockIdx.x;
  const int tid = threadIdx.x;
  __shared__ double SH[SH_TOT];
  __shared__ double Msh[NSUP * 26];

  double* x = SH + OFF_X;
  double* s = SH + OFF_S;
  double* z = SH + OFF_Z;
  double* bx = SH + OFF_BX;
  double* rx = SH + OFF_RX;
  double* rz = SH + OFF_RZ;
  double* tt = SH + OFF_TT;
  double* dd = SH + OFF_DD;
  double* dxa = SH + OFF_DXA;
  double* dsa = SH + OFF_DSA;
  double* dza = SH + OFF_DZA;
  double* rsc = SH + OFF_RSC;
  double* dxc = SH + OFF_DXC;
  double* dsc = SH + OFF_DSC;
  double* dzc = SH + OFF_DZC;
  double* yv = SH + OFF_YV;
  double* ry = SH + OFF_RY;
  double* dya = SH + OFF_DYA;
  double* dyc = SH + OFF_DYC;
  double* z125 = SH + OFF_Z125;
  double* z25 = SH + OFF_Z25;
  double* SC = SH + OFF_SC;

  for (int idx = tid; idx < NSUP * 26; idx += TPB)
    Msh[idx] = Mg[(size_t)b * 650 + idx];

  if (tid < NZV) {
    const int i = tid / 5, k = tid - i * 5;
    const double oh = (k == (i % 5)) ? 1.0 : 0.0;
    rx[tid] = -oh;
    rz[tid] = -0.1 * oh;
    dd[tid] = 1.0;
    rsc[tid] = 0.0;
    z125[tid] = 0.0;
  } else if (tid >= 128 && tid < 153) {
    const int i = tid - 128;
    ry[i] = 0.0;
    z25[i] = 0.0;
  }
  if (tid == 0) SC[0] = 1e300;
  __syncthreads();

  factorize(Msh, SH, tid);
  kkt_solve(Msh, SH, rx, rsc, rz, ry, x, s, z, yv, tid);

  {
    const double ms = bred(s, NZV, 1, SC, tid);
    if (ms < 0.0 && tid < NZV) s[tid] -= (ms - 1.0);
    const double mz = bred(z, NZV, 1, SC, tid);
    if (mz < 0.0 && tid < NZV) z[tid] -= (mz - 1.0);
  }
  if (tid < NZV) bx[tid] = x[tid];

#pragma unroll 1
  for (int it = 0; it < 3; ++it) {
    __syncthreads();
    if (tid < NZV) {
      const int i = tid / 5, k = tid - i * 5;
      double acc = 0.0;
#pragma unroll
      for (int j = 0; j < 25; ++j) acc += Msh[i * 26 + j] * x[j * 5 + k];
      const double oh = (k == (i % 5)) ? 1.0 : 0.0;
      rx[tid] = yv[i] + z[tid] + acc - oh;
      rz[tid] = x[tid] + s[tid] - 0.1 * oh;
      tt[tid] = s[tid] * z[tid];
    } else if (tid >= 128 && tid < 153) {
      const int i = tid - 128;
      double acc = 0.0;
#pragma unroll
      for (int k = 0; k < 5; ++k) acc += x[i * 5 + k];
      ry[i] = acc;
    }
    const double szsum = bred(tt, NZV, 0, SC, tid);
    if (tid < NZV) tt[tid] = rx[tid] * rx[tid];
    const double snx = bred(tt, NZV, 0, SC, tid);
    if (tid < NZV) tt[tid] = rz[tid] * rz[tid];
    const double snz = bred(tt, NZV, 0, SC, tid);
    if (tid < 25) tt[tid] = ry[tid] * ry[tid];
    const double sny = bred(tt, 25, 0, SC, tid);
    const double mu = fabs(szsum) / 125.0;
    const double res = sqrt(snz + 1e-30) + sqrt(sny + 1e-30) +
                       sqrt(snx + 1e-30) + 125.0 * mu;
    if (tid == 0) {
      if (res < SC[0]) { SC[0] = res; SC[1] = 1.0; } else SC[1] = 0.0;
    }
    __syncthreads();
    if (SC[1] != 0.0 && tid < NZV) bx[tid] = x[tid];
    if (it == 2) break;
    __syncthreads();

    if (tid < NZV) dd[tid] = z[tid] / s[tid];
    __syncthreads();
    factorize(Msh, SH, tid);
    kkt_solve(Msh, SH, rx, z, rz, ry, dxa, dsa, dza, dya, tid);
    if (tid < NZV) {
      const double a1 = (dza[tid] < 0.0) ? (-z[tid] / dza[tid]) : 1e12;
      const double a2 = (dsa[tid] < 0.0) ? (-s[tid] / dsa[tid]) : 1e12;
      tt[tid] = fmin(a1, a2);
    }
    const double aff = fmin(bred(tt, NZV, 1, SC, tid), 1.0);
    if (tid < NZV)
      tt[tid] = (s[tid] + aff * dsa[tid]) * (z[tid] + aff * dza[tid]);
    const double num = bred(tt, NZV, 0, SC, tid);
    const double sg = num / szsum;
    const double musig = mu * (sg * sg * sg);
    if (tid < NZV) rsc[tid] = (-musig + dsa[tid] * dza[tid]) / s[tid];
    __syncthreads();
    kkt_solve(Msh, SH, z125, rsc, z125, z25, dxc, dsc, dzc, dyc, tid);
    if (tid < NZV) {
      const double ddx = dxa[tid] + dxc[tid];
      const double dds = dsa[tid] + dsc[tid];
      const double ddz = dza[tid] + dzc[tid];
      dxa[tid] = ddx; dsa[tid] = dds; dza[tid] = ddz;
      const double a1 = (ddz < 0.0) ? (-z[tid] / ddz) : 1e12;
      const double a2 = (dds < 0.0) ? (-s[tid] / dds) : 1e12;
      tt[tid] = fmin(a1, a2);
    } else if (tid >= 128 && tid < 153) {
      const int i = tid - 128;
      dya[i] += dyc[i];
    }
    const double al = fmin(0.999 * bred(tt, NZV, 1, SC, tid), 1.0);
    if (tid < NZV) {
      x[tid] += al * dxa[tid];
      s[tid] += al * dsa[tid];
      z[tid] += al * dza[tid];
    } else if (tid >= 128 && tid < 153) {
      const int i = tid - 128;
      yv[i] += al * dya[i];
    }
  }
  __syncthreads();
  if (tid < NZV) xout[(size_t)b * NZV + tid] = (float)bx[tid];
}

// =====================================================================
// Kernel 3 (v2): out[q][w2] = fq_q . xf[w2], xf[w2] = sum_s x[s][w2] ft_s.
// Eliminates the 75x25 dots matrix + per-support shfl reductions (5x
// fewer MACs). Query dot accumulated in fp64 to keep rounding below the
// per-support-dot version's.
// =====================================================================
__global__ void __launch_bounds__(TPB) out_kernel(
    const float* __restrict__ test, const float* __restrict__ train,
    const int* __restrict__ usimple, const float* __restrict__ xin,
    float* __restrict__ out) {
  const int b = blockIdx.x;
  const int tid = threadIdx.x;
  const int lane = tid & 63;
  const int w = tid >> 6;
  const bool us = (usimple[0] != 0);

  __shared__ float ftl[NSUP * DF];   // 64000 B
  __shared__ float xf[NWAY * DF];    // 12800 B
  __shared__ float xls[NZV];

  if (tid < NZV) xls[tid] = xin[(size_t)b * NZV + tid];

  // stage transformed + normalized train rows; wave w -> rows 5w..5w+4
  const float* tb = train + (size_t)b * NSUP * DF;
#pragma unroll
  for (int j = 0; j < 5; ++j) {
    const int r = 5 * w + j;
    float qv[10];
    float ss = 0.0f;
#pragma unroll
    for (int c = 0; c < 10; ++c) {
      float v = tb[r * DF + lane + 64 * c];
      if (us) v = simple_tf(v);
      qv[c] = v;
      ss += v * v;
    }
#pragma unroll
    for (int off = 32; off > 0; off >>= 1) ss += __shfl_xor(ss, off);
    const float sc = 1.0f / fmaxf(sqrtf(ss), 1e-12f);
#pragma unroll
    for (int c = 0; c < 10; ++c) ftl[r * DF + lane + 64 * c] = qv[c] * sc;
  }
  __syncthreads();

  // xf build: wave w handles way w
  {
    float xs[25];
#pragma unroll
    for (int s = 0; s < 25; ++s) xs[s] = xls[s * 5 + w];  // broadcast reads
#pragma unroll
    for (int c = 0; c < 10; ++c) {
      const int d = lane + 64 * c;
      float acc = 0.0f;
#pragma unroll
      for (int s = 0; s < 25; ++s) acc += xs[s] * ftl[s * DF + d];
      xf[w * DF + d] = acc;
    }
  }
  __syncthreads();

  // queries: wave w handles q = w, w+5, ..., w+70
  const float* qb = test + (size_t)b * NQ * DF;
  for (int qq = 0; qq < 15; ++qq) {
    const int q = w + 5 * qq;
    const float* qr = qb + (size_t)q * DF;
    float nrm = 0.0f;
    double a0 = 0.0, a1 = 0.0, a2 = 0.0, a3 = 0.0, a4 = 0.0;
#pragma unroll
    for (int c = 0; c < 10; ++c) {
      const int d = lane + 64 * c;
      float v = qr[d];
      if (us) v = simple_tf(v);
      nrm += v * v;
      const double vd = (double)v;
      a0 += vd * (double)xf[0 * DF + d];
      a1 += vd * (double)xf[1 * DF + d];
      a2 += vd * (double)xf[2 * DF + d];
      a3 += vd * (double)xf[3 * DF + d];
      a4 += vd * (double)xf[4 * DF + d];
    }
#pragma unroll
    for (int off = 32; off > 0; off >>= 1) {
      nrm += __shfl_xor(nrm, off);
      a0 += __shfl_xor(a0, off);
      a1 += __shfl_xor(a1, off);
      a2 += __shfl_xor(a2, off);
      a3 += __shfl_xor(a3, off);
      a4 += __shfl_xor(a4, off);
    }
    if (lane == 0) {
      const float sc = 1.0f / fmaxf(sqrtf(nrm), 1e-12f);
      float* op = out + ((size_t)b * NQ + q) * 5;
      op[0] = (float)a0 * sc;
      op[1] = (float)a1 * sc;
      op[2] = (float)a2 * sc;
      op[3] = (float)a3 * sc;
      op[4] = (float)a4 * sc;
    }
  }
}

// =====================================================================
extern "C" void kernel_launch(void* const* d_in, const int* in_sizes, int n_in,
                              void* d_out, int out_size, void* d_ws,
                              size_t ws_size, hipStream_t stream) {
  const float* ftest = (const float*)d_in[0];
  const float* ftrain = (const float*)d_in[1];
  const int* usimple = (const int*)d_in[4];
  float* out = (float*)d_out;
  const int B = in_sizes[1] / (NSUP * DF);

  double* Mg = (double*)d_ws;                               // B * 650 doubles
  float* xws = (float*)((char*)d_ws + (size_t)B * 650 * sizeof(double));

  feat_kernel<<<dim3(B), dim3(TPB), 0, stream>>>(ftrain, usimple, Mg);
  qp_kernel<<<dim3(B), dim3(TPB), 0, stream>>>(Mg, xws);
  out_kernel<<<dim3(B), dim3(TPB), 0, stream>>>(ftest, ftrain, usimple, xws, out);
}

// Round 6
// 533.247 us; speedup vs baseline: 1.2776x; 1.2776x over previous
//
#include <hip/hip_runtime.h>
#include <math.h>

#define NWAY 5
#define NSUP 25
#define NZV  125
#define DF   640
#define NQ   75
#define TPB  320
#define FSTR 644   // FT row stride (floats)

// ---------------- shared-memory offsets for qp state (in doubles) ----------
#define OFF_WINV 3250   // (HINV at 0: 5*650)
#define OFF_X    3900
#define OFF_S    4028
#define OFF_Z    4156
#define OFF_BX   4284
#define OFF_RX   4412
#define OFF_RZ   4540
#define OFF_TT   4668
#define OFF_C1   4796
#define OFF_DD   4924
#define OFF_VV   5052
#define OFF_DXA  5180
#define OFF_DSA  5308
#define OFF_DZA  5436
#define OFF_RSC  5564
#define OFF_DXC  5692
#define OFF_DSC  5820
#define OFF_DZC  5948
#define OFF_YV   6076
#define OFF_RY   6108
#define OFF_C2   6140
#define OFF_GG   6172
#define OFF_DYA  6204
#define OFF_DYC  6236
#define OFF_Z125 6268
#define OFF_Z25  6396
#define OFF_SC   6428
#define SH_TOT   6448   // 51584 B; FT needs 25*644*4 = 64400 B -> RAW = 64400

__device__ __forceinline__ float simple_tf(float x) {
  float tp = fmaxf(x, 0.0f) + 1e-5f;
  float tn = fmaxf(-x, 0.0f) + 1e-5f;
  float lp = __logf(__builtin_amdgcn_rcpf(tp) + 1.0f);
  float ln_ = __logf(__builtin_amdgcn_rcpf(tn) + 1.0f);
  float pos = __expf(-1.3f * __logf(lp));
  float neg = __expf(-1.3f * __logf(ln_));
  return pos - neg;
}

// Constant-lane fp64 broadcast via v_readlane (VALU, off the LDS pipe).
__device__ __forceinline__ double bcastd(double v, const int srclane) {
  const int lo = __builtin_amdgcn_readlane(__double2loint(v), srclane);
  const int hi = __builtin_amdgcn_readlane(__double2hiint(v), srclane);
  return __hiloint2double(hi, lo);
}

// In-place Gauss-Jordan inversion of 25x25 SPD, lane = column.
template <int J>
__device__ __forceinline__ void gj_pivot(double (&a)[25], const int lane) {
  const double djj = bcastd(a[J], J);
  const double pinv = 1.0 / djj;
  a[J] = ((lane == J) ? 1.0 : a[J]) * pinv;
#pragma unroll
  for (int r = 0; r < 25; ++r) {
    if (r != J) {
      const double f = bcastd(a[r], J);
      a[r] = ((lane == J) ? 0.0 : a[r]) - f * a[J];
    }
  }
}
template <int J>
__device__ __forceinline__ void gj_all(double (&a)[25], const int lane) {
  if constexpr (J < 25) {
    gj_pivot<J>(a, lane);
    gj_all<J + 1>(a, lane);
  }
}
__device__ __forceinline__ void gjinv25(double (&a)[25], const int lane) {
  gj_all<0>(a, lane);
}

// Stage transform+l2norm train rows into FT (stride FSTR). Wave w: rows w,w+5,..
__device__ __forceinline__ void build_FT(const float* __restrict__ tb,
                                         const bool us, float* FT,
                                         const int lane, const int w) {
#pragma unroll
  for (int jj = 0; jj < 5; ++jj) {
    const int r = w + 5 * jj;
    float qv[10];
    float ss = 0.0f;
#pragma unroll
    for (int c = 0; c < 10; ++c) {
      float v = tb[r * DF + lane + 64 * c];
      if (us) v = simple_tf(v);
      qv[c] = v;
      ss += v * v;
    }
#pragma unroll
    for (int off = 32; off > 0; off >>= 1) ss += __shfl_xor(ss, off);
    const float sc = 1.0f / fmaxf(sqrtf(ss), 1e-12f);
#pragma unroll
    for (int c = 0; c < 10; ++c) FT[r * FSTR + lane + 64 * c] = qv[c] * sc;
  }
}

__device__ __forceinline__ void factorize(const double* Msh, double* SH,
                                          const int tid) {
  const int lane = tid & 63;
  const int w = tid >> 6;
  const double* dd = SH + OFF_DD;
  double* Hinv = SH;              // OFF_HINV = 0
  double* Winv = SH + OFF_WINV;
  {
    double a[25];
#pragma unroll
    for (int j = 0; j < 25; ++j) a[j] = 0.0;
    if (lane < 25) {
#pragma unroll
      for (int j = 0; j < 25; ++j)
        a[j] = Msh[lane * 26 + j] + ((j == lane) ? dd[lane * 5 + w] : 0.0);
    }
    gjinv25(a, lane);
    if (lane < 25) {
#pragma unroll
      for (int i = 0; i < 25; ++i) Hinv[w * 650 + i * 26 + lane] = a[i];
    }
  }
  __syncthreads();
  for (int idx = tid; idx < 625; idx += TPB) {
    const int i = idx / 25, r = idx - i * 25;
    double acc = 0.0;
#pragma unroll
    for (int k = 0; k < 5; ++k) acc += Hinv[k * 650 + i * 26 + r];
    Winv[i * 26 + r] = acc;
  }
  __syncthreads();
  if (w == 0) {
    double a[25];
#pragma unroll
    for (int j = 0; j < 25; ++j) a[j] = 0.0;
    if (lane < 25) {
#pragma unroll
      for (int j = 0; j < 25; ++j) a[j] = Winv[lane * 26 + j];
    }
    gjinv25(a, lane);
    if (lane < 25) {
#pragma unroll
      for (int i = 0; i < 25; ++i) Winv[i * 26 + lane] = a[i];
    }
  }
  __syncthreads();
}

__device__ __forceinline__ void kkt_solve(
    const double* Msh, double* SH, const double* rx, const double* rs,
    const double* rz, const double* ry, double* dx, double* ds, double* dz,
    double* dy, const int tid) {
  const int lane = tid & 63;
  const int w = tid >> 6;
  const double* dd = SH + OFF_DD;
  const double* Hinv = SH;
  const double* Winv = SH + OFF_WINV;
  double* tt = SH + OFF_TT;
  double* c1 = SH + OFF_C1;
  double* c2 = SH + OFF_C2;
  double* vv = SH + OFF_VV;
  double* gg = SH + OFF_GG;

  if (tid < NZV) tt[tid] = rz[tid] - rs[tid] / dd[tid];
  __syncthreads();
  if (tid < NZV) {
    const int i = tid / 5, k = tid - i * 5;
    double acc = -rx[tid];
#pragma unroll
    for (int j = 0; j < 25; ++j) acc += Msh[i * 26 + j] * tt[j * 5 + k];
    c1[tid] = acc;
  } else if (tid >= 128 && tid < 153) {
    const int i = tid - 128;
    double acc = -ry[i];
#pragma unroll
    for (int k = 0; k < 5; ++k) acc += tt[i * 5 + k];
    c2[i] = acc;
  }
  __syncthreads();
  if (lane < 25) {
    double acc = 0.0;
#pragma unroll
    for (int j = 0; j < 25; ++j)
      acc += Hinv[w * 650 + lane * 26 + j] * c1[j * 5 + w];
    vv[lane * 5 + w] = acc;
  }
  __syncthreads();
  if (tid < 25) {
    double acc = -c2[tid];
#pragma unroll
    for (int k = 0; k < 5; ++k) acc += vv[tid * 5 + k];
    gg[tid] = acc;
  }
  __syncthreads();
  if (tid < 25) {
    double acc = 0.0;
#pragma unroll
    for (int r = 0; r < 25; ++r) acc += Winv[tid * 26 + r] * gg[r];
    dy[tid] = acc;
  }
  __syncthreads();
  if (lane < 25) {
    double acc = 0.0;
#pragma unroll
    for (int j = 0; j < 25; ++j) acc += Hinv[w * 650 + lane * 26 + j] * dy[j];
    const int v = lane * 5 + w;
    const double u = vv[v] - acc;
    const double dzv = dd[v] * u;
    dz[v] = dzv;
    dx[v] = u - tt[v];
    ds[v] = (-rs[v] - dzv) / dd[v];
  }
  __syncthreads();
}

__device__ __forceinline__ double bred(const double* buf, int n, int ismin,
                                       double* SC, const int tid) {
  __syncthreads();
  if (tid < 64) {
    double acc = ismin ? 1e300 : 0.0;
    for (int m = tid; m < n; m += 64) {
      const double v = buf[m];
      acc = ismin ? fmin(acc, v) : (acc + v);
    }
#pragma unroll
    for (int off = 32; off > 0; off >>= 1) {
      const double o = __shfl_xor(acc, off);
      acc = ismin ? fmin(acc, o) : (acc + o);
    }
    if (tid == 0) SC[15] = acc;
  }
  __syncthreads();
  return SC[15];
}

// =====================================================================
// Merged kernel: FT build -> Gram/M -> QP -> FT rebuild -> xf write.
// FT (64.4 KB) aliases the QP state SH (51.6 KB): FT is rebuilt after
// the QP (~2 us) instead of coexisting, keeping LDS ~70 KB -> 2 blk/CU.
// =====================================================================
__global__ void __launch_bounds__(TPB, 2) qp_kernel(
    const float* __restrict__ train, const int* __restrict__ usimple,
    float* __restrict__ xfg) {
  const int b = blockIdx.x;
  const int tid = threadIdx.x;
  const int lane = tid & 63;
  const int w = tid >> 6;
  const bool us = (usimple[0] != 0);

  __shared__ __align__(16) unsigned char RAW[NSUP * FSTR * 4];  // 64400 B
  __shared__ double Msh[NSUP * 26];
  __shared__ float bxs[NZV];
  float* FT = (float*)RAW;
  double* SH = (double*)RAW;

  double* x = SH + OFF_X;
  double* s = SH + OFF_S;
  double* z = SH + OFF_Z;
  double* bx = SH + OFF_BX;
  double* rx = SH + OFF_RX;
  double* rz = SH + OFF_RZ;
  double* tt = SH + OFF_TT;
  double* dd = SH + OFF_DD;
  double* dxa = SH + OFF_DXA;
  double* dsa = SH + OFF_DSA;
  double* dza = SH + OFF_DZA;
  double* rsc = SH + OFF_RSC;
  double* dxc = SH + OFF_DXC;
  double* dsc = SH + OFF_DSC;
  double* dzc = SH + OFF_DZC;
  double* yv = SH + OFF_YV;
  double* ry = SH + OFF_RY;
  double* dya = SH + OFF_DYA;
  double* dyc = SH + OFF_DYC;
  double* z125 = SH + OFF_Z125;
  double* z25 = SH + OFF_Z25;
  double* SC = SH + OFF_SC;

  const float* tb = train + (size_t)b * NSUP * DF;

  // ---- phase 1: FT = transformed + normalized train rows ----
  build_FT(tb, us, FT, lane, w);
  __syncthreads();

  // ---- phase 2: M = FT FT^T + I (fp64 accumulate) ----
  for (int pi = tid; pi < 325; pi += TPB) {
    int i = 0, rem = pi;
    while (rem >= NSUP - i) { rem -= NSUP - i; ++i; }
    const int j = i + rem;
    const float4* ra = (const float4*)(FT + i * FSTR);
    const float4* rb = (const float4*)(FT + j * FSTR);
    double acc = (i == j) ? 1.0 : 0.0;
    for (int c = 0; c < 160; ++c) {
      float4 av = ra[c], bv = rb[c];
      acc += (double)av.x * bv.x + (double)av.y * bv.y +
             (double)av.z * bv.z + (double)av.w * bv.w;
    }
    Msh[i * 26 + j] = acc;
    if (i != j) Msh[j * 26 + i] = acc;
  }
  __syncthreads();

  // ---- phase 3: QP (overwrites FT region with SH state) ----
  if (tid < NZV) {
    const int i = tid / 5, k = tid - i * 5;
    const double oh = (k == (i % 5)) ? 1.0 : 0.0;
    rx[tid] = -oh;
    rz[tid] = -0.1 * oh;
    dd[tid] = 1.0;
    rsc[tid] = 0.0;
    z125[tid] = 0.0;
  } else if (tid >= 128 && tid < 153) {
    const int i = tid - 128;
    ry[i] = 0.0;
    z25[i] = 0.0;
  }
  if (tid == 0) SC[0] = 1e300;
  __syncthreads();

  factorize(Msh, SH, tid);
  kkt_solve(Msh, SH, rx, rsc, rz, ry, x, s, z, yv, tid);

  {
    const double ms = bred(s, NZV, 1, SC, tid);
    if (ms < 0.0 && tid < NZV) s[tid] -= (ms - 1.0);
    const double mz = bred(z, NZV, 1, SC, tid);
    if (mz < 0.0 && tid < NZV) z[tid] -= (mz - 1.0);
  }
  if (tid < NZV) bx[tid] = x[tid];

#pragma unroll 1
  for (int it = 0; it < 3; ++it) {
    __syncthreads();
    if (tid < NZV) {
      const int i = tid / 5, k = tid - i * 5;
      double acc = 0.0;
#pragma unroll
      for (int j = 0; j < 25; ++j) acc += Msh[i * 26 + j] * x[j * 5 + k];
      const double oh = (k == (i % 5)) ? 1.0 : 0.0;
      rx[tid] = yv[i] + z[tid] + acc - oh;
      rz[tid] = x[tid] + s[tid] - 0.1 * oh;
      tt[tid] = s[tid] * z[tid];
    } else if (tid >= 128 && tid < 153) {
      const int i = tid - 128;
      double acc = 0.0;
#pragma unroll
      for (int k = 0; k < 5; ++k) acc += x[i * 5 + k];
      ry[i] = acc;
    }
    const double szsum = bred(tt, NZV, 0, SC, tid);
    if (tid < NZV) tt[tid] = rx[tid] * rx[tid];
    const double snx = bred(tt, NZV, 0, SC, tid);
    if (tid < NZV) tt[tid] = rz[tid] * rz[tid];
    const double snz = bred(tt, NZV, 0, SC, tid);
    if (tid < 25) tt[tid] = ry[tid] * ry[tid];
    const double sny = bred(tt, 25, 0, SC, tid);
    const double mu = fabs(szsum) / 125.0;
    const double res = sqrt(snz + 1e-30) + sqrt(sny + 1e-30) +
                       sqrt(snx + 1e-30) + 125.0 * mu;
    if (tid == 0) {
      if (res < SC[0]) { SC[0] = res; SC[1] = 1.0; } else SC[1] = 0.0;
    }
    __syncthreads();
    if (SC[1] != 0.0 && tid < NZV) bx[tid] = x[tid];
    if (it == 2) break;
    __syncthreads();

    if (tid < NZV) dd[tid] = z[tid] / s[tid];
    __syncthreads();
    factorize(Msh, SH, tid);
    kkt_solve(Msh, SH, rx, z, rz, ry, dxa, dsa, dza, dya, tid);
    if (tid < NZV) {
      const double a1 = (dza[tid] < 0.0) ? (-z[tid] / dza[tid]) : 1e12;
      const double a2 = (dsa[tid] < 0.0) ? (-s[tid] / dsa[tid]) : 1e12;
      tt[tid] = fmin(a1, a2);
    }
    const double aff = fmin(bred(tt, NZV, 1, SC, tid), 1.0);
    if (tid < NZV)
      tt[tid] = (s[tid] + aff * dsa[tid]) * (z[tid] + aff * dza[tid]);
    const double num = bred(tt, NZV, 0, SC, tid);
    const double sg = num / szsum;
    const double musig = mu * (sg * sg * sg);
    if (tid < NZV) rsc[tid] = (-musig + dsa[tid] * dza[tid]) / s[tid];
    __syncthreads();
    kkt_solve(Msh, SH, z125, rsc, z125, z25, dxc, dsc, dzc, dyc, tid);
    if (tid < NZV) {
      const double ddx = dxa[tid] + dxc[tid];
      const double dds = dsa[tid] + dsc[tid];
      const double ddz = dza[tid] + dzc[tid];
      dxa[tid] = ddx; dsa[tid] = dds; dza[tid] = ddz;
      const double a1 = (ddz < 0.0) ? (-z[tid] / ddz) : 1e12;
      const double a2 = (dds < 0.0) ? (-s[tid] / dds) : 1e12;
      tt[tid] = fmin(a1, a2);
    } else if (tid >= 128 && tid < 153) {
      const int i = tid - 128;
      dya[i] += dyc[i];
    }
    const double al = fmin(0.999 * bred(tt, NZV, 1, SC, tid), 1.0);
    if (tid < NZV) {
      x[tid] += al * dxa[tid];
      s[tid] += al * dsa[tid];
      z[tid] += al * dza[tid];
    } else if (tid >= 128 && tid < 153) {
      const int i = tid - 128;
      yv[i] += al * dya[i];
    }
  }
  __syncthreads();

  // ---- phase 4: save best_x to floats, rebuild FT, write xf ----
  if (tid < NZV) bxs[tid] = (float)bx[tid];
  __syncthreads();                 // bx read complete before FT overwrite
  build_FT(tb, us, FT, lane, w);
  __syncthreads();
  {
    float xs[25];
#pragma unroll
    for (int s_ = 0; s_ < 25; ++s_) xs[s_] = bxs[s_ * 5 + w];
#pragma unroll
    for (int c = 0; c < 10; ++c) {
      const int d = lane + 64 * c;
      float acc = 0.0f;
#pragma unroll
      for (int s_ = 0; s_ < 25; ++s_) acc += xs[s_] * FT[s_ * FSTR + d];
      xfg[((size_t)b * NWAY + w) * DF + d] = acc;
    }
  }
}

// =====================================================================
// Output kernel: out[q][w2] = (fq_q/|fq_q|) . xf[w2].  Grid B*3, each
// block handles 25 queries; LDS = xf only (12.8 KB) -> 6 blocks/CU,
// 30 waves/CU (the R5 version had 77 KB LDS -> 2 blocks/CU, latency-
// bound at occupancy 14%).
// =====================================================================
__global__ void __launch_bounds__(TPB) out_kernel(
    const float* __restrict__ test, const int* __restrict__ usimple,
    const float* __restrict__ xfg, float* __restrict__ out) {
  const int bb = blockIdx.x;
  const int b = bb / 3;
  const int t = bb - 3 * b;
  const int tid = threadIdx.x;
  const int lane = tid & 63;
  const int w = tid >> 6;
  const bool us = (usimple[0] != 0);

  __shared__ float xfs[NWAY * DF];
  for (int i = tid; i < NWAY * DF; i += TPB)
    xfs[i] = xfg[(size_t)b * NWAY * DF + i];
  __syncthreads();

  const float* qb = test + (size_t)b * NQ * DF;
#pragma unroll
  for (int jj = 0; jj < 5; ++jj) {
    const int q = 25 * t + w + 5 * jj;
    const float* qr = qb + (size_t)q * DF;
    float nrm = 0.0f;
    double a0 = 0.0, a1 = 0.0, a2 = 0.0, a3 = 0.0, a4 = 0.0;
#pragma unroll
    for (int c = 0; c < 10; ++c) {
      const int d = lane + 64 * c;
      float v = qr[d];
      if (us) v = simple_tf(v);
      nrm += v * v;
      const double vd = (double)v;
      a0 += vd * (double)xfs[0 * DF + d];
      a1 += vd * (double)xfs[1 * DF + d];
      a2 += vd * (double)xfs[2 * DF + d];
      a3 += vd * (double)xfs[3 * DF + d];
      a4 += vd * (double)xfs[4 * DF + d];
    }
#pragma unroll
    for (int off = 32; off > 0; off >>= 1) {
      nrm += __shfl_xor(nrm, off);
      a0 += __shfl_xor(a0, off);
      a1 += __shfl_xor(a1, off);
      a2 += __shfl_xor(a2, off);
      a3 += __shfl_xor(a3, off);
      a4 += __shfl_xor(a4, off);
    }
    if (lane == 0) {
      const float sc = 1.0f / fmaxf(sqrtf(nrm), 1e-12f);
      float* op = out + ((size_t)b * NQ + q) * 5;
      op[0] = (float)a0 * sc;
      op[1] = (float)a1 * sc;
      op[2] = (float)a2 * sc;
      op[3] = (float)a3 * sc;
      op[4] = (float)a4 * sc;
    }
  }
}

// =====================================================================
extern "C" void kernel_launch(void* const* d_in, const int* in_sizes, int n_in,
                              void* d_out, int out_size, void* d_ws,
                              size_t ws_size, hipStream_t stream) {
  const float* ftest = (const float*)d_in[0];
  const float* ftrain = (const float*)d_in[1];
  const int* usimple = (const int*)d_in[4];
  float* out = (float*)d_out;
  const int B = in_sizes[1] / (NSUP * DF);

  float* xfg = (float*)d_ws;   // B * 5 * 640 floats

  qp_kernel<<<dim3(B), dim3(TPB), 0, stream>>>(ftrain, usimple, xfg);
  out_kernel<<<dim3(B * 3), dim3(TPB), 0, stream>>>(ftest, usimple, xfg, out);
}